// Round 5
// baseline (518.053 us; speedup 1.0000x reference)
//
#include <hip/hip_runtime.h>
#include <math.h>
#include <cstdint>
#include <cstddef>

// B=2, T=1024, C=4096, H=32, G=8, D=128, rep=4, M=B*T=2048
typedef __bf16 bf16_t;
typedef __bf16 bf16x8 __attribute__((ext_vector_type(8)));
typedef __bf16 bf16x4 __attribute__((ext_vector_type(4)));
typedef float f32x4 __attribute__((ext_vector_type(4)));
typedef float f32x16 __attribute__((ext_vector_type(16)));

#define MFMA16(a, b, c) __builtin_amdgcn_mfma_f32_16x16x32_bf16(a, b, c, 0, 0, 0)
#define MFMA32(a, b, c) __builtin_amdgcn_mfma_f32_32x32x16_bf16(a, b, c, 0, 0, 0)

__device__ __forceinline__ void stage16(const void* g, void* l) {
  __builtin_amdgcn_global_load_lds(
      (const __attribute__((address_space(1))) unsigned int*)g,
      (__attribute__((address_space(3))) unsigned int*)l, 16, 0, 0);
}

__device__ __forceinline__ bf16x4 shfl_xor32_b64(bf16x4 v) {
  union { bf16x4 h; unsigned int u[2]; } a;
  a.h = v;
  a.u[0] = __shfl_xor(a.u[0], 32);
  a.u[1] = __shfl_xor(a.u[1], 32);
  return a.h;
}

__device__ __forceinline__ bf16x8 cat44(bf16x4 lo, bf16x4 hiv) {
  bf16x8 r;
  r[0] = lo[0]; r[1] = lo[1]; r[2] = lo[2]; r[3] = lo[3];
  r[4] = hiv[0]; r[5] = hiv[1]; r[6] = hiv[2]; r[7] = hiv[3];
  return r;
}

// ---------------- convert fp32 -> bf16 ----------------
__global__ void k_convert(const float* __restrict__ in, bf16_t* __restrict__ out, int n) {
  int i = (blockIdx.x * blockDim.x + threadIdx.x) * 4;
  if (i >= n) return;
  float4 v = *(const float4*)(in + i);
  out[i + 0] = (bf16_t)v.x;
  out[i + 1] = (bf16_t)v.y;
  out[i + 2] = (bf16_t)v.z;
  out[i + 3] = (bf16_t)v.w;
}

// ---------------- transpose+convert: out[c][r] = in[r][c] ----------------
__global__ void k_transpose(const float* __restrict__ in, bf16_t* __restrict__ out,
                            int R, int C) {
  __shared__ float t[32][33];
  int r0 = blockIdx.y * 32, c0 = blockIdx.x * 32;
  int tx = threadIdx.x, ty = threadIdx.y;
#pragma unroll
  for (int i = 0; i < 4; i++)
    t[ty + i * 8][tx] = in[(size_t)(r0 + ty + i * 8) * C + (c0 + tx)];
  __syncthreads();
#pragma unroll
  for (int i = 0; i < 4; i++)
    out[(size_t)(c0 + ty + i * 8) * R + (r0 + tx)] = (bf16_t)t[tx][ty + i * 8];
}

// ---------------- GEMM: 128x128 tile, BK=64, MFMA32 core, dbuf single-barrier ----
// K-loop: { barrier; prefetch chunk c+1 -> buf^1; compute chunk c from buf^0 }.
// The compiler's vmcnt(0)-before-barrier then retires loads issued one full
// compute phase earlier (cheap), instead of just-issued ones (the m97 stall).
// LDS rows 128 B = 8 chunks of 16 B, physical chunk p holds logical p^(row&7).
// MODE 0: Cout = A*BT^T + bias (fp32). MODE 1: QKV epilogue (no transcendentals):
//   n0<4096 -> Qr [B][H][T][128]; <5120 -> Kr [B][G][T][128]; else Vt [B][G][128][T].
template <int MODE>
__global__ __launch_bounds__(256) void k_gemm(
    const bf16_t* __restrict__ A, const bf16_t* __restrict__ BT,
    float* __restrict__ Cout, const float* __restrict__ bias,
    bf16_t* __restrict__ Qr, bf16_t* __restrict__ Kr, bf16_t* __restrict__ Vt,
    int M, int N, int K) {
  __shared__ __align__(16) bf16_t As[2][128 * 64];  // 2 x 16 KB
  __shared__ __align__(16) bf16_t Bs[2][128 * 64];  // 2 x 16 KB
  int tid = threadIdx.x;
  int w = tid >> 6, lane = tid & 63, hi = lane >> 5, l32 = lane & 31;
  int n0 = blockIdx.x * 128, m0 = blockIdx.y * 128;
  int wm = (w >> 1) * 64, wn = (w & 1) * 64;
  const char* Ab = (const char*)A + (size_t)m0 * K * 2;
  const char* Bb = (const char*)BT + (size_t)n0 * K * 2;
  size_t rb = (size_t)K * 2;

  auto stage_chunk = [&](int k0, int buf) {
#pragma unroll
    for (int it = 0; it < 4; ++it) {
      int P = it * 256 + tid;          // 128 rows x 8 chunk-slots
      int row = P >> 3, ph = P & 7;
      int c = ph ^ (row & 7);
      stage16(Ab + (size_t)row * rb + (size_t)k0 * 2 + c * 16, (char*)As[buf] + P * 16);
      stage16(Bb + (size_t)row * rb + (size_t)k0 * 2 + c * 16, (char*)Bs[buf] + P * 16);
    }
  };

  f32x16 acc[2][2] = {};
  stage_chunk(0, 0);
  int nch = K >> 6;
  for (int cidx = 0; cidx < nch; ++cidx) {
    __syncthreads();                   // publishes buf[cidx&1]; drain is one phase old
    if (cidx + 1 < nch) stage_chunk((cidx + 1) << 6, (cidx + 1) & 1);
    const char* Asb = (const char*)As[cidx & 1];
    const char* Bsb = (const char*)Bs[cidx & 1];
#pragma unroll
    for (int s = 0; s < 4; ++s) {
      bf16x8 af[2], bfr[2];
#pragma unroll
      for (int i = 0; i < 2; ++i) {
        int row = wm + i * 32 + l32;
        int ph = (s * 2 + hi) ^ (row & 7);
        af[i] = *(const bf16x8*)(Asb + row * 128 + ph * 16);
      }
#pragma unroll
      for (int j = 0; j < 2; ++j) {
        int row = wn + j * 32 + l32;
        int ph = (s * 2 + hi) ^ (row & 7);
        bfr[j] = *(const bf16x8*)(Bsb + row * 128 + ph * 16);
      }
#pragma unroll
      for (int i = 0; i < 2; ++i)
#pragma unroll
        for (int j = 0; j < 2; ++j)
          acc[i][j] = MFMA32(af[i], bfr[j], acc[i][j]);
    }
  }

  // 32x32 C/D layout: col = l32, row = (reg&3) + 8*(reg>>2) + 4*hi
  if (MODE == 0) {
#pragma unroll
    for (int i = 0; i < 2; i++)
#pragma unroll
      for (int j = 0; j < 2; j++) {
        int col = n0 + wn + j * 32 + l32;
        float bv = bias[col];
#pragma unroll
        for (int reg = 0; reg < 16; ++reg) {
          int row = m0 + wm + i * 32 + (reg & 3) + 8 * (reg >> 2) + 4 * hi;
          Cout[(size_t)row * N + col] = acc[i][j][reg] + bv;
        }
      }
  } else if (n0 < 5120) {
    bf16_t* dst;
    int NH, cb;
    if (n0 < 4096) { dst = Qr; NH = 32; cb = 0; }
    else           { dst = Kr; NH = 8;  cb = 4096; }
#pragma unroll
    for (int i = 0; i < 2; i++)
#pragma unroll
      for (int j = 0; j < 2; j++) {
        int cc = (n0 - cb) + wn + j * 32 + l32;
        int hh = cc >> 7, d = cc & 127;
#pragma unroll
        for (int reg = 0; reg < 16; ++reg) {
          int row = m0 + wm + i * 32 + (reg & 3) + 8 * (reg >> 2) + 4 * hi;
          int t = row & 1023, bb = row >> 10;
          dst[((size_t)(bb * NH + hh) * 1024 + t) * 128 + d] = (bf16_t)acc[i][j][reg];
        }
      }
  } else {
    int bb = m0 >> 10;
#pragma unroll
    for (int i = 0; i < 2; i++)
#pragma unroll
      for (int j = 0; j < 2; j++) {
        int cc = (n0 - 5120) + wn + j * 32 + l32;
        int gg = cc >> 7, d = cc & 127;
#pragma unroll
        for (int rg = 0; rg < 4; ++rg) {
          int t0 = ((m0 + wm + i * 32) & 1023) + 8 * rg + 4 * hi;
          bf16x4 v4;
#pragma unroll
          for (int e = 0; e < 4; ++e) v4[e] = (bf16_t)acc[i][j][rg * 4 + e];
          *(bf16x4*)(Vt + ((size_t)(bb * 8 + gg) * 128 + d) * 1024 + t0) = v4;
        }
      }
  }
}

// ---------------- in-place RoPE on [B][NH][T][128] bf16 --------------------------
__global__ __launch_bounds__(256) void k_rope(bf16_t* __restrict__ buf, int NH,
                                              float scale) {
  int bt = blockIdx.x;
  int t = bt & 1023, b = bt >> 10;
  int dp = threadIdx.x & 63;
  int h0 = threadIdx.x >> 6;
  float freq = __expf(-(float)dp * (9.210340371976184f / 64.0f));  // ln(1e4)/64
  float ang = (float)t * freq;
  float sn, cs;
  sincosf(ang, &sn, &cs);
  int hper = NH >> 2;
  for (int i = 0; i < hper; ++i) {
    int h = h0 * hper + i;
    size_t idx = ((size_t)(b * NH + h) * 1024 + t) * 128 + dp * 2;
    float xr = (float)buf[idx], xi = (float)buf[idx + 1];
    buf[idx]     = (bf16_t)((xr * cs - xi * sn) * scale);
    buf[idx + 1] = (bf16_t)((xr * sn + xi * cs) * scale);
  }
}

// ---------------- flash attention (32x32x16 MFMA, S^T, dbuf single-barrier) ------
// LDS 64 KB: region A = K/V buf0 (32 KB), region B = Qs (read once) aliased as
// K/V buf1. Per k-tile: one barrier, prefetch kt+1 into buf^1, compute buf^0.
__global__ __launch_bounds__(256) void k_attn(
    const bf16_t* __restrict__ Q, const bf16_t* __restrict__ K,
    const bf16_t* __restrict__ V, bf16_t* __restrict__ O) {
  __shared__ __align__(16) bf16_t lds[32768];  // 64 KB
  bf16_t* Qs = lds + 16384;                    // aliases K/V buf1
  int tid = threadIdx.x;
  int w = tid >> 6, lane = tid & 63, hi = lane >> 5, l32 = lane & 31;
  int u = blockIdx.x;
  int rr = u >> 8, s = u & 255;
  int pp0 = s & 7, h = s >> 3, b = rr;
  int tile = rr ? 7 - pp0 : pp0;   // complementary causal load balance
  int g = h >> 2;

  const char* Qg = (const char*)Q + ((size_t)(b * 32 + h) * 1024 + tile * 128) * 256;
  const char* Kg = (const char*)K + (size_t)(b * 8 + g) * 1024 * 256;
  const char* Vg = (const char*)V + (size_t)(b * 8 + g) * 128 * 2048;

#pragma unroll
  for (int it = 0; it < 8; ++it) {
    int P = it * 256 + tid;
    int row = P >> 4, ph = P & 15, c = ph ^ (row & 15);
    stage16(Qg + row * 256 + c * 16, (char*)Qs + P * 16);
  }
  __syncthreads();

  bf16x8 qf[8];
#pragma unroll
  for (int kk = 0; kk < 8; ++kk) {
    int row = w * 32 + l32;
    int ph = (kk * 2 + hi) ^ (l32 & 15);
    qf[kk] = *(const bf16x8*)((const char*)Qs + row * 256 + ph * 16);
  }

  auto stageKV = [&](int k0, int buf) {
    char* Kb_ = (char*)(lds + buf * 16384);
    char* Vb_ = (char*)(lds + buf * 16384 + 8192);
#pragma unroll
    for (int it = 0; it < 4; ++it) {
      int P = it * 256 + tid;
      int row = P >> 4, ph = P & 15, c = ph ^ (row & 15);
      stage16(Kg + (size_t)(k0 + row) * 256 + c * 16, Kb_ + P * 16);
    }
#pragma unroll
    for (int it = 0; it < 4; ++it) {
      int P = it * 256 + tid;
      int row = P >> 3, ph = P & 7, c = ph ^ (row & 7);
      stage16(Vg + (size_t)row * 2048 + (size_t)k0 * 2 + c * 16, Vb_ + P * 16);
    }
  };

  f32x16 Oacc[4] = {};
  float m_i = -INFINITY, l_i = 0.0f;
  int q0t = tile * 128 + w * 32;
  int qg = q0t + l32;
  int ktmax = 2 * tile + 1;

  stageKV(0, 0);
  for (int kt = 0; kt <= ktmax; ++kt) {
    int k0 = kt * 64;
    __syncthreads();                    // publishes KV buf[kt&1] (issued last iter)
    if (kt < ktmax) stageKV(k0 + 64, (kt + 1) & 1);
    if (k0 > q0t + 31) continue;        // wave fully masked this k-tile
    const char* Ksb = (const char*)(lds + (kt & 1) * 16384);
    const char* Vsb = (const char*)(lds + (kt & 1) * 16384 + 8192);

    f32x16 Sa[2];
#pragma unroll
    for (int kt2 = 0; kt2 < 2; ++kt2) {
      f32x16 sacc = {};
#pragma unroll
      for (int kk = 0; kk < 8; ++kk) {
        int row = kt2 * 32 + l32;
        int ph = (kk * 2 + hi) ^ (l32 & 15);
        bf16x8 kf = *(const bf16x8*)(Ksb + row * 256 + ph * 16);
        sacc = MFMA32(kf, qf[kk], sacc);
      }
      Sa[kt2] = sacc;
    }

    bool needmask = (k0 + 63) > q0t;    // wave-uniform
    float sv[32];
    float mx = -INFINITY;
#pragma unroll
    for (int kt2 = 0; kt2 < 2; ++kt2)
#pragma unroll
      for (int reg = 0; reg < 16; ++reg) {
        float v = Sa[kt2][reg];
        if (needmask) {
          int key = k0 + kt2 * 32 + (reg & 3) + 8 * (reg >> 2) + 4 * hi;
          v = (key <= qg) ? v : -INFINITY;
        }
        sv[kt2 * 16 + reg] = v;
        mx = fmaxf(mx, v);
      }
    mx = fmaxf(mx, __shfl_xor(mx, 32));
    float mn = fmaxf(m_i, mx);
    float alpha = __expf(m_i - mn);
    float sum = 0.0f;
#pragma unroll
    for (int e = 0; e < 32; ++e) {
      float pe = __expf(sv[e] - mn);
      sv[e] = pe;
      sum += pe;
    }
    sum += __shfl_xor(sum, 32);
    m_i = mn;
    l_i = l_i * alpha + sum;

    bf16x8 pf[4];
#pragma unroll
    for (int kt2 = 0; kt2 < 2; ++kt2) {
      bf16x4 pk[4];
#pragma unroll
      for (int gg = 0; gg < 4; ++gg) {
#pragma unroll
        for (int e = 0; e < 4; ++e) pk[gg][e] = (bf16_t)sv[kt2 * 16 + 4 * gg + e];
      }
      bf16x4 X = shfl_xor32_b64(hi ? pk[0] : pk[1]);
      bf16x4 Y = shfl_xor32_b64(hi ? pk[2] : pk[3]);
      pf[2 * kt2]     = (hi == 0) ? cat44(pk[0], X) : cat44(X, pk[1]);
      pf[2 * kt2 + 1] = (hi == 0) ? cat44(pk[2], Y) : cat44(Y, pk[3]);
    }

#pragma unroll
    for (int nt = 0; nt < 4; ++nt) {
      f32x16 o = Oacc[nt];
#pragma unroll
      for (int reg = 0; reg < 16; ++reg) o[reg] *= alpha;
#pragma unroll
      for (int kk = 0; kk < 4; ++kk) {
        int row = nt * 32 + l32;
        int ph = (kk * 2 + hi) ^ (row & 7);
        bf16x8 vf = *(const bf16x8*)(Vsb + row * 128 + ph * 16);
        o = MFMA32(vf, pf[kk], o);
      }
      Oacc[nt] = o;
    }
  }

  float inv = 1.0f / l_i;
  bf16_t* Ob = O + ((size_t)(b * 1024 + qg)) * 4096 + h * 128;
#pragma unroll
  for (int nt = 0; nt < 4; ++nt)
#pragma unroll
    for (int gg = 0; gg < 4; ++gg) {
      bf16x4 o4;
#pragma unroll
      for (int e = 0; e < 4; ++e) o4[e] = (bf16_t)(Oacc[nt][4 * gg + e] * inv);
      *(bf16x4*)(Ob + nt * 32 + 8 * gg + 4 * hi) = o4;
    }
}

extern "C" void kernel_launch(void* const* d_in, const int* in_sizes, int n_in,
                              void* d_out, int out_size, void* d_ws, size_t ws_size,
                              hipStream_t stream) {
  const float* x  = (const float*)d_in[0];   // [2,1024,4096]
  const float* Wq = (const float*)d_in[1];   // [4096,4096]
  const float* Wk = (const float*)d_in[2];   // [4096,1024]
  const float* Wv = (const float*)d_in[3];   // [4096,1024]
  const float* Wo = (const float*)d_in[4];   // [4096,4096]
  const float* bo = (const float*)d_in[5];   // [4096]
  float* out = (float*)d_out;                // [2,1024,4096]

  char* p = (char*)d_ws;
  bf16_t* Xb    = (bf16_t*)p; p += (size_t)2048 * 4096 * 2;  // 16 MB
  bf16_t* WqkvT = (bf16_t*)p; p += (size_t)6144 * 4096 * 2;  // 48 MB
  bf16_t* WoT   = (bf16_t*)p; p += (size_t)4096 * 4096 * 2;  // 32 MB
  bf16_t* Qb    = (bf16_t*)p; p += (size_t)2048 * 4096 * 2;  // 16 MB
  bf16_t* Kb    = (bf16_t*)p; p += (size_t)2048 * 1024 * 2;  //  4 MB
  bf16_t* Vt    = (bf16_t*)p; p += (size_t)2048 * 1024 * 2;  //  4 MB
  bf16_t* Ob    = (bf16_t*)p; p += (size_t)2048 * 4096 * 2;  // 16 MB

  dim3 tb(32, 8);
  k_convert<<<8192, 256, 0, stream>>>(x, Xb, 2048 * 4096);
  k_transpose<<<dim3(128, 128), tb, 0, stream>>>(Wq, WqkvT, 4096, 4096);
  k_transpose<<<dim3(32, 128),  tb, 0, stream>>>(Wk, WqkvT + (size_t)4096 * 4096, 4096, 1024);
  k_transpose<<<dim3(32, 128),  tb, 0, stream>>>(Wv, WqkvT + (size_t)5120 * 4096, 4096, 1024);
  k_transpose<<<dim3(128, 128), tb, 0, stream>>>(Wo, WoT, 4096, 4096);
  // fused QKV projection (raw) + permuted layouts
  k_gemm<1><<<dim3(48, 16), 256, 0, stream>>>(Xb, WqkvT, nullptr, nullptr,
                                              Qb, Kb, Vt, 2048, 6144, 4096);
  // in-place rope (Q pre-scaled by 1/sqrt(128))
  k_rope<<<2048, 256, 0, stream>>>(Qb, 32, 0.08838834764831845f);
  k_rope<<<2048, 256, 0, stream>>>(Kb, 8, 1.0f);
  k_attn<<<512, 256, 0, stream>>>(Qb, Kb, Vt, Ob);
  k_gemm<0><<<dim3(32, 16), 256, 0, stream>>>(Ob, WoT, out, bo,
                                              nullptr, nullptr, nullptr, 2048, 4096, 4096);
}

// Round 6
// 471.486 us; speedup vs baseline: 1.0988x; 1.0988x over previous
//
#include <hip/hip_runtime.h>
#include <math.h>
#include <cstdint>
#include <cstddef>

// B=2, T=1024, C=4096, H=32, G=8, D=128, rep=4, M=B*T=2048
typedef __bf16 bf16_t;
typedef __bf16 bf16x8 __attribute__((ext_vector_type(8)));
typedef __bf16 bf16x4 __attribute__((ext_vector_type(4)));
typedef float f32x4 __attribute__((ext_vector_type(4)));
typedef float f32x16 __attribute__((ext_vector_type(16)));

#define MFMA32(a, b, c) __builtin_amdgcn_mfma_f32_32x32x16_bf16(a, b, c, 0, 0, 0)

__device__ __forceinline__ void stage16(const void* g, void* l) {
  __builtin_amdgcn_global_load_lds(
      (const __attribute__((address_space(1))) unsigned int*)g,
      (__attribute__((address_space(3))) unsigned int*)l, 16, 0, 0);
}

__device__ __forceinline__ bf16x4 shfl_xor32_b64(bf16x4 v) {
  union { bf16x4 h; unsigned int u[2]; } a;
  a.h = v;
  a.u[0] = __shfl_xor(a.u[0], 32);
  a.u[1] = __shfl_xor(a.u[1], 32);
  return a.h;
}

__device__ __forceinline__ bf16x8 cat44(bf16x4 lo, bf16x4 hiv) {
  bf16x8 r;
  r[0] = lo[0]; r[1] = lo[1]; r[2] = lo[2]; r[3] = lo[3];
  r[4] = hiv[0]; r[5] = hiv[1]; r[6] = hiv[2]; r[7] = hiv[3];
  return r;
}

// ---------------- convert fp32 -> bf16 ----------------
__global__ void k_convert(const float* __restrict__ in, bf16_t* __restrict__ out, int n) {
  int i = (blockIdx.x * blockDim.x + threadIdx.x) * 4;
  if (i >= n) return;
  float4 v = *(const float4*)(in + i);
  out[i + 0] = (bf16_t)v.x;
  out[i + 1] = (bf16_t)v.y;
  out[i + 2] = (bf16_t)v.z;
  out[i + 3] = (bf16_t)v.w;
}

// ---------------- transpose+convert: out[c][r] = in[r][c] ----------------
__global__ void k_transpose(const float* __restrict__ in, bf16_t* __restrict__ out,
                            int R, int C) {
  __shared__ float t[32][33];
  int r0 = blockIdx.y * 32, c0 = blockIdx.x * 32;
  int tx = threadIdx.x, ty = threadIdx.y;
#pragma unroll
  for (int i = 0; i < 4; i++)
    t[ty + i * 8][tx] = in[(size_t)(r0 + ty + i * 8) * C + (c0 + tx)];
  __syncthreads();
#pragma unroll
  for (int i = 0; i < 4; i++)
    out[(size_t)(c0 + ty + i * 8) * R + (r0 + tx)] = (bf16_t)t[tx][ty + i * 8];
}

// ---------------- GEMM: 128x128 tile, BK=64, MFMA32 core, SINGLE buffer ----------
// Round-4 2-barrier m97 structure (3 blocks/CU implicit overlap beats explicit
// dbuf at 64 KB — m132 lesson, re-measured round 5). MFMA32 core: 16 MFMA32 +
// 16 ds_read_b128 per chunk (vs 32 MFMA16) — fewer matrix cycles + half the
// frag-read VALU. LDS rows 128 B = 8 chunks of 16 B; phys chunk p of row r
// holds logical p^(r&7); any aligned 8-lane frag-read group covers all 32 banks.
// MODE 0: Cout = A*BT^T + bias (fp32). MODE 1: QKV epilogue (no transcendentals):
//   n0<4096 -> Qr [B][H][T][128]; <5120 -> Kr [B][G][T][128]; else Vt [B][G][128][T].
template <int MODE>
__global__ __launch_bounds__(256) void k_gemm(
    const bf16_t* __restrict__ A, const bf16_t* __restrict__ BT,
    float* __restrict__ Cout, const float* __restrict__ bias,
    bf16_t* __restrict__ Qr, bf16_t* __restrict__ Kr, bf16_t* __restrict__ Vt,
    int M, int N, int K) {
  __shared__ __align__(16) bf16_t As[128 * 64];  // 16 KB
  __shared__ __align__(16) bf16_t Bs[128 * 64];  // 16 KB
  int tid = threadIdx.x;
  int w = tid >> 6, lane = tid & 63, hi = lane >> 5, l32 = lane & 31;
  int n0 = blockIdx.x * 128, m0 = blockIdx.y * 128;
  int wm = (w >> 1) * 64, wn = (w & 1) * 64;
  const char* Ab = (const char*)A + (size_t)m0 * K * 2;
  const char* Bb = (const char*)BT + (size_t)n0 * K * 2;
  size_t rb = (size_t)K * 2;

  f32x16 acc[2][2] = {};
  for (int k0 = 0; k0 < K; k0 += 64) {
    __syncthreads();
#pragma unroll
    for (int it = 0; it < 4; ++it) {
      int P = it * 256 + tid;          // 128 rows x 8 chunk-slots
      int row = P >> 3, ph = P & 7;
      int c = ph ^ (row & 7);          // logical chunk staged into phys slot ph
      stage16(Ab + (size_t)row * rb + (size_t)k0 * 2 + c * 16, (char*)As + P * 16);
      stage16(Bb + (size_t)row * rb + (size_t)k0 * 2 + c * 16, (char*)Bs + P * 16);
    }
    __syncthreads();
#pragma unroll
    for (int s = 0; s < 4; ++s) {
      bf16x8 af[2], bfr[2];
#pragma unroll
      for (int i = 0; i < 2; ++i) {
        int row = wm + i * 32 + l32;
        int ph = (s * 2 + hi) ^ (row & 7);
        af[i] = *(const bf16x8*)((const char*)As + row * 128 + ph * 16);
      }
#pragma unroll
      for (int j = 0; j < 2; ++j) {
        int row = wn + j * 32 + l32;
        int ph = (s * 2 + hi) ^ (row & 7);
        bfr[j] = *(const bf16x8*)((const char*)Bs + row * 128 + ph * 16);
      }
#pragma unroll
      for (int i = 0; i < 2; ++i)
#pragma unroll
        for (int j = 0; j < 2; ++j)
          acc[i][j] = MFMA32(af[i], bfr[j], acc[i][j]);
    }
  }

  // 32x32 C/D layout: col = l32, row = (reg&3) + 8*(reg>>2) + 4*hi  (verified r5)
  if (MODE == 0) {
#pragma unroll
    for (int i = 0; i < 2; i++)
#pragma unroll
      for (int j = 0; j < 2; j++) {
        int col = n0 + wn + j * 32 + l32;
        float bv = bias[col];
#pragma unroll
        for (int reg = 0; reg < 16; ++reg) {
          int row = m0 + wm + i * 32 + (reg & 3) + 8 * (reg >> 2) + 4 * hi;
          Cout[(size_t)row * N + col] = acc[i][j][reg] + bv;
        }
      }
  } else if (n0 < 5120) {
    bf16_t* dst;
    int NH, cb;
    if (n0 < 4096) { dst = Qr; NH = 32; cb = 0; }
    else           { dst = Kr; NH = 8;  cb = 4096; }
#pragma unroll
    for (int i = 0; i < 2; i++)
#pragma unroll
      for (int j = 0; j < 2; j++) {
        int cc = (n0 - cb) + wn + j * 32 + l32;
        int hh = cc >> 7, d = cc & 127;
#pragma unroll
        for (int reg = 0; reg < 16; ++reg) {
          int row = m0 + wm + i * 32 + (reg & 3) + 8 * (reg >> 2) + 4 * hi;
          int t = row & 1023, bb = row >> 10;
          dst[((size_t)(bb * NH + hh) * 1024 + t) * 128 + d] = (bf16_t)acc[i][j][reg];
        }
      }
  } else {
    int bb = m0 >> 10;
#pragma unroll
    for (int i = 0; i < 2; i++)
#pragma unroll
      for (int j = 0; j < 2; j++) {
        int cc = (n0 - 5120) + wn + j * 32 + l32;
        int gg = cc >> 7, d = cc & 127;
#pragma unroll
        for (int rg = 0; rg < 4; ++rg) {
          int t0 = ((m0 + wm + i * 32) & 1023) + 8 * rg + 4 * hi;
          bf16x4 v4;
#pragma unroll
          for (int e = 0; e < 4; ++e) v4[e] = (bf16_t)acc[i][j][rg * 4 + e];
          *(bf16x4*)(Vt + ((size_t)(bb * 8 + gg) * 128 + d) * 1024 + t0) = v4;
        }
      }
  }
}

// ---------------- in-place RoPE on [B][NH][T][128] bf16 --------------------------
__global__ __launch_bounds__(256) void k_rope(bf16_t* __restrict__ buf, int NH,
                                              float scale) {
  int bt = blockIdx.x;
  int t = bt & 1023, b = bt >> 10;
  int dp = threadIdx.x & 63;
  int h0 = threadIdx.x >> 6;
  float freq = __expf(-(float)dp * (9.210340371976184f / 64.0f));  // ln(1e4)/64
  float ang = (float)t * freq;
  float sn, cs;
  sincosf(ang, &sn, &cs);
  int hper = NH >> 2;
  for (int i = 0; i < hper; ++i) {
    int h = h0 * hper + i;
    size_t idx = ((size_t)(b * NH + h) * 1024 + t) * 128 + dp * 2;
    float xr = (float)buf[idx], xi = (float)buf[idx + 1];
    buf[idx]     = (bf16_t)((xr * cs - xi * sn) * scale);
    buf[idx + 1] = (bf16_t)((xr * sn + xi * cs) * scale);
  }
}

// ---------------- flash attention (32x32x16 MFMA, S^T, dbuf single-barrier) ------
// LDS 64 KB: region A = K/V buf0 (32 KB), region B = Qs (read once) aliased as
// K/V buf1. Per k-tile: one barrier, prefetch kt+1 into buf^1, compute buf^0.
// (Kept from round 5 — attention's long compute phase hides the prefetch.)
__global__ __launch_bounds__(256) void k_attn(
    const bf16_t* __restrict__ Q, const bf16_t* __restrict__ K,
    const bf16_t* __restrict__ V, bf16_t* __restrict__ O) {
  __shared__ __align__(16) bf16_t lds[32768];  // 64 KB
  bf16_t* Qs = lds + 16384;                    // aliases K/V buf1
  int tid = threadIdx.x;
  int w = tid >> 6, lane = tid & 63, hi = lane >> 5, l32 = lane & 31;
  int u = blockIdx.x;
  int rr = u >> 8, s = u & 255;
  int pp0 = s & 7, h = s >> 3, b = rr;
  int tile = rr ? 7 - pp0 : pp0;   // complementary causal load balance
  int g = h >> 2;

  const char* Qg = (const char*)Q + ((size_t)(b * 32 + h) * 1024 + tile * 128) * 256;
  const char* Kg = (const char*)K + (size_t)(b * 8 + g) * 1024 * 256;
  const char* Vg = (const char*)V + (size_t)(b * 8 + g) * 128 * 2048;

#pragma unroll
  for (int it = 0; it < 8; ++it) {
    int P = it * 256 + tid;
    int row = P >> 4, ph = P & 15, c = ph ^ (row & 15);
    stage16(Qg + row * 256 + c * 16, (char*)Qs + P * 16);
  }
  __syncthreads();

  bf16x8 qf[8];
#pragma unroll
  for (int kk = 0; kk < 8; ++kk) {
    int row = w * 32 + l32;
    int ph = (kk * 2 + hi) ^ (l32 & 15);
    qf[kk] = *(const bf16x8*)((const char*)Qs + row * 256 + ph * 16);
  }

  auto stageKV = [&](int k0, int buf) {
    char* Kb_ = (char*)(lds + buf * 16384);
    char* Vb_ = (char*)(lds + buf * 16384 + 8192);
#pragma unroll
    for (int it = 0; it < 4; ++it) {
      int P = it * 256 + tid;
      int row = P >> 4, ph = P & 15, c = ph ^ (row & 15);
      stage16(Kg + (size_t)(k0 + row) * 256 + c * 16, Kb_ + P * 16);
    }
#pragma unroll
    for (int it = 0; it < 4; ++it) {
      int P = it * 256 + tid;
      int row = P >> 3, ph = P & 7, c = ph ^ (row & 7);
      stage16(Vg + (size_t)row * 2048 + (size_t)k0 * 2 + c * 16, Vb_ + P * 16);
    }
  };

  f32x16 Oacc[4] = {};
  float m_i = -INFINITY, l_i = 0.0f;
  int q0t = tile * 128 + w * 32;
  int qg = q0t + l32;
  int ktmax = 2 * tile + 1;

  stageKV(0, 0);
  for (int kt = 0; kt <= ktmax; ++kt) {
    int k0 = kt * 64;
    __syncthreads();                    // publishes KV buf[kt&1] (issued last iter)
    if (kt < ktmax) stageKV(k0 + 64, (kt + 1) & 1);
    if (k0 > q0t + 31) continue;        // wave fully masked this k-tile
    const char* Ksb = (const char*)(lds + (kt & 1) * 16384);
    const char* Vsb = (const char*)(lds + (kt & 1) * 16384 + 8192);

    f32x16 Sa[2];
#pragma unroll
    for (int kt2 = 0; kt2 < 2; ++kt2) {
      f32x16 sacc = {};
#pragma unroll
      for (int kk = 0; kk < 8; ++kk) {
        int row = kt2 * 32 + l32;
        int ph = (kk * 2 + hi) ^ (l32 & 15);
        bf16x8 kf = *(const bf16x8*)(Ksb + row * 256 + ph * 16);
        sacc = MFMA32(kf, qf[kk], sacc);
      }
      Sa[kt2] = sacc;
    }

    bool needmask = (k0 + 63) > q0t;    // wave-uniform
    float sv[32];
    float mx = -INFINITY;
#pragma unroll
    for (int kt2 = 0; kt2 < 2; ++kt2)
#pragma unroll
      for (int reg = 0; reg < 16; ++reg) {
        float v = Sa[kt2][reg];
        if (needmask) {
          int key = k0 + kt2 * 32 + (reg & 3) + 8 * (reg >> 2) + 4 * hi;
          v = (key <= qg) ? v : -INFINITY;
        }
        sv[kt2 * 16 + reg] = v;
        mx = fmaxf(mx, v);
      }
    mx = fmaxf(mx, __shfl_xor(mx, 32));
    float mn = fmaxf(m_i, mx);
    float alpha = __expf(m_i - mn);
    float sum = 0.0f;
#pragma unroll
    for (int e = 0; e < 32; ++e) {
      float pe = __expf(sv[e] - mn);
      sv[e] = pe;
      sum += pe;
    }
    sum += __shfl_xor(sum, 32);
    m_i = mn;
    l_i = l_i * alpha + sum;

    bf16x8 pf[4];
#pragma unroll
    for (int kt2 = 0; kt2 < 2; ++kt2) {
      bf16x4 pk[4];
#pragma unroll
      for (int gg = 0; gg < 4; ++gg) {
#pragma unroll
        for (int e = 0; e < 4; ++e) pk[gg][e] = (bf16_t)sv[kt2 * 16 + 4 * gg + e];
      }
      bf16x4 X = shfl_xor32_b64(hi ? pk[0] : pk[1]);
      bf16x4 Y = shfl_xor32_b64(hi ? pk[2] : pk[3]);
      pf[2 * kt2]     = (hi == 0) ? cat44(pk[0], X) : cat44(X, pk[1]);
      pf[2 * kt2 + 1] = (hi == 0) ? cat44(pk[2], Y) : cat44(Y, pk[3]);
    }

#pragma unroll
    for (int nt = 0; nt < 4; ++nt) {
      f32x16 o = Oacc[nt];
#pragma unroll
      for (int reg = 0; reg < 16; ++reg) o[reg] *= alpha;
#pragma unroll
      for (int kk = 0; kk < 4; ++kk) {
        int row = nt * 32 + l32;
        int ph = (kk * 2 + hi) ^ (row & 7);
        bf16x8 vf = *(const bf16x8*)(Vsb + row * 128 + ph * 16);
        o = MFMA32(vf, pf[kk], o);
      }
      Oacc[nt] = o;
    }
  }

  float inv = 1.0f / l_i;
  bf16_t* Ob = O + ((size_t)(b * 1024 + qg)) * 4096 + h * 128;
#pragma unroll
  for (int nt = 0; nt < 4; ++nt)
#pragma unroll
    for (int gg = 0; gg < 4; ++gg) {
      bf16x4 o4;
#pragma unroll
      for (int e = 0; e < 4; ++e) o4[e] = (bf16_t)(Oacc[nt][4 * gg + e] * inv);
      *(bf16x4*)(Ob + nt * 32 + 8 * gg + 4 * hi) = o4;
    }
}

extern "C" void kernel_launch(void* const* d_in, const int* in_sizes, int n_in,
                              void* d_out, int out_size, void* d_ws, size_t ws_size,
                              hipStream_t stream) {
  const float* x  = (const float*)d_in[0];   // [2,1024,4096]
  const float* Wq = (const float*)d_in[1];   // [4096,4096]
  const float* Wk = (const float*)d_in[2];   // [4096,1024]
  const float* Wv = (const float*)d_in[3];   // [4096,1024]
  const float* Wo = (const float*)d_in[4];   // [4096,4096]
  const float* bo = (const float*)d_in[5];   // [4096]
  float* out = (float*)d_out;                // [2,1024,4096]

  char* p = (char*)d_ws;
  bf16_t* Xb    = (bf16_t*)p; p += (size_t)2048 * 4096 * 2;  // 16 MB
  bf16_t* WqkvT = (bf16_t*)p; p += (size_t)6144 * 4096 * 2;  // 48 MB
  bf16_t* WoT   = (bf16_t*)p; p += (size_t)4096 * 4096 * 2;  // 32 MB
  bf16_t* Qb    = (bf16_t*)p; p += (size_t)2048 * 4096 * 2;  // 16 MB
  bf16_t* Kb    = (bf16_t*)p; p += (size_t)2048 * 1024 * 2;  //  4 MB
  bf16_t* Vt    = (bf16_t*)p; p += (size_t)2048 * 1024 * 2;  //  4 MB
  bf16_t* Ob    = (bf16_t*)p; p += (size_t)2048 * 4096 * 2;  // 16 MB

  dim3 tb(32, 8);
  k_convert<<<8192, 256, 0, stream>>>(x, Xb, 2048 * 4096);
  k_transpose<<<dim3(128, 128), tb, 0, stream>>>(Wq, WqkvT, 4096, 4096);
  k_transpose<<<dim3(32, 128),  tb, 0, stream>>>(Wk, WqkvT + (size_t)4096 * 4096, 4096, 1024);
  k_transpose<<<dim3(32, 128),  tb, 0, stream>>>(Wv, WqkvT + (size_t)5120 * 4096, 4096, 1024);
  k_transpose<<<dim3(128, 128), tb, 0, stream>>>(Wo, WoT, 4096, 4096);
  // fused QKV projection (raw) + permuted layouts
  k_gemm<1><<<dim3(48, 16), 256, 0, stream>>>(Xb, WqkvT, nullptr, nullptr,
                                              Qb, Kb, Vt, 2048, 6144, 4096);
  // in-place rope (Q pre-scaled by 1/sqrt(128))
  k_rope<<<2048, 256, 0, stream>>>(Qb, 32, 0.08838834764831845f);
  k_rope<<<2048, 256, 0, stream>>>(Kb, 8, 1.0f);
  k_attn<<<512, 256, 0, stream>>>(Qb, Kb, Vt, Ob);
  k_gemm<0><<<dim3(32, 16), 256, 0, stream>>>(Ob, WoT, out, bo,
                                              nullptr, nullptr, nullptr, 2048, 4096, 4096);
}